// Round 3
// baseline (790.140 us; speedup 1.0000x reference)
//
#include <hip/hip_runtime.h>
#include <math.h>

#define TILE 64
#define HALO 12
#define BW   (TILE + 2*HALO)   // 88
#define BUFN (BW*BW)           // 7744
#define NPIX (TILE*TILE/256)   // 16 interior pixels per thread
#define IMG  1024
#define NITER 11               // 1 init + 10 loop iterations

__device__ __forceinline__ float sigmoidf(float x) {
    return 1.0f / (1.0f + __expf(-x));
}

// Computes soft_skeleton for one 64x64 tile (+12 halo) entirely in LDS.
// MODE 0: src is float*, apply sigmoid. MODE 1: src is int*, cast to float.
// On exit: val[q] = image value at interior pixel q, skel[q] = skeleton value.
// Out-of-image pixels carry sentinel 2.0 (acts as +inf for erode); the dilate
// masks values >1.5 to -1.0 (acts as -inf). All real values are in [0,1].
template<int MODE>
__device__ void run_skel(const void* __restrict__ src, long base, int gr0, int gc0,
                         int tid, float* A, float* B,
                         float val[NPIX], float skel[NPIX]) {
    // ---- load tile + halo ----
    for (int i = tid; i < BUFN; i += 256) {
        int r = i / BW, c = i - r*BW;
        int gr = gr0 + r, gc = gc0 + c;
        float v = 2.0f;
        if ((unsigned)gr < IMG && (unsigned)gc < IMG) {
            long idx = base + (long)gr*IMG + gc;
            if (MODE == 0) v = sigmoidf(((const float*)src)[idx]);
            else           v = (float)(((const int*)src)[idx]);
        }
        A[i] = v;
    }
    __syncthreads();

    // ---- save interior values (needed for the cross-term reductions) ----
    #pragma unroll
    for (int q = 0; q < NPIX; ++q) {
        int i = tid + (q << 8);
        int r = HALO + (i >> 6), c = HALO + (i & 63);
        val[q] = A[r*BW + c];
    }

    // ---- erode chain + on-the-fly open + skeleton update ----
    // e_j valid on [j, BW-j)^2.  delta_j = relu(e_{j-1} - dilate(e_j)) at interior.
    for (int j = 1; j <= NITER; ++j) {
        const int lo = j, hi = BW - j;
        // erode A -> B over shrinking region
        for (int i = tid; i < BUFN; i += 256) {
            int r = i / BW, c = i - r*BW;
            if (r >= lo && r < hi && c >= lo && c < hi) {
                float ctr  = A[i];
                float vmin = fminf(A[i - BW], A[i + BW]);
                float hmin = fminf(A[i - 1],  A[i + 1]);
                float e = fminf(ctr, fminf(vmin, hmin));
                int gr = gr0 + r, gc = gc0 + c;
                if (!((unsigned)gr < IMG && (unsigned)gc < IMG)) e = 2.0f; // keep +inf sentinel
                B[i] = e;
            }
        }
        __syncthreads();
        // dilate(B) at interior pixels; update skel in registers
        #pragma unroll
        for (int q = 0; q < NPIX; ++q) {
            int i = tid + (q << 8);
            int r = HALO + (i >> 6), c = HALO + (i & 63);
            int p = r*BW + c;
            float m = -1.0f;
            #pragma unroll
            for (int dr = -1; dr <= 1; ++dr) {
                #pragma unroll
                for (int dc = -1; dc <= 1; ++dc) {
                    float v = B[p + dr*BW + dc];
                    v = (v > 1.5f) ? -1.0f : v;   // out-of-image acts as -inf
                    m = fmaxf(m, v);
                }
            }
            float ctr   = A[p];                   // e_{j-1} at p (always in-image)
            float delta = fmaxf(ctr - m, 0.0f);
            if (j == 1) skel[q] = delta;          // skel init: relu(img - open(img))
            else        skel[q] += fmaxf(delta - skel[q]*delta, 0.0f);
        }
        __syncthreads();
        float* t = A; A = B; B = t;
    }
}

__global__ __launch_bounds__(256)
void cl_dice_main(const float* __restrict__ pred, const int* __restrict__ targ,
                  float* __restrict__ ws) {
    __shared__ float bufA[BUFN];
    __shared__ float bufB[BUFN];
    const int tid = threadIdx.x;
    const int gr0 = blockIdx.y * TILE - HALO;
    const int gc0 = blockIdx.x * TILE - HALO;
    const long base = (long)blockIdx.z * (long)(IMG * IMG);

    float val_p[NPIX], skel_p[NPIX], val_t[NPIX], skel_t[NPIX];
    run_skel<0>(pred, base, gr0, gc0, tid, bufA, bufB, val_p, skel_p);
    run_skel<1>(targ, base, gr0, gc0, tid, bufA, bufB, val_t, skel_t);

    // ---- per-thread partial sums ----
    float s[7] = {0,0,0,0,0,0,0};
    #pragma unroll
    for (int q = 0; q < NPIX; ++q) {
        float p = val_p[q], t = val_t[q], kp = skel_p[q], kt = skel_t[q];
        s[0] += kp;       // sum(skel_pred)
        s[1] += kp * t;   // sum(skel_pred * target)
        s[2] += kt;       // sum(skel_target)
        s[3] += kt * p;   // sum(skel_target * pred_prob)
        s[4] += p * t;    // intersection
        s[5] += p;        // sum(pred_prob)
        s[6] += t;        // sum(target)
    }

    // ---- block reduction (wave shuffle -> LDS -> per-block partial) ----
    __syncthreads();   // done with bufA/bufB as stencil buffers
    #pragma unroll
    for (int k = 0; k < 7; ++k) {
        float v = s[k];
        v += __shfl_down(v, 32);
        v += __shfl_down(v, 16);
        v += __shfl_down(v, 8);
        v += __shfl_down(v, 4);
        v += __shfl_down(v, 2);
        v += __shfl_down(v, 1);
        if ((tid & 63) == 0) bufA[(tid >> 6) * 8 + k] = v;
    }
    __syncthreads();
    if (tid < 7) {
        float v = bufA[tid] + bufA[8 + tid] + bufA[16 + tid] + bufA[24 + tid];
        int blk = (blockIdx.z * gridDim.y + blockIdx.y) * gridDim.x + blockIdx.x;
        ws[blk * 8 + tid] = v;
    }
}

__global__ __launch_bounds__(256)
void cl_dice_finalize(const float* __restrict__ ws, float* __restrict__ out, int nblk) {
    __shared__ float red[4][8];
    int tid = threadIdx.x;
    float acc[7] = {0,0,0,0,0,0,0};
    for (int i = tid; i < nblk; i += 256) {
        #pragma unroll
        for (int k = 0; k < 7; ++k) acc[k] += ws[i * 8 + k];
    }
    #pragma unroll
    for (int k = 0; k < 7; ++k) {
        float v = acc[k];
        v += __shfl_down(v, 32);
        v += __shfl_down(v, 16);
        v += __shfl_down(v, 8);
        v += __shfl_down(v, 4);
        v += __shfl_down(v, 2);
        v += __shfl_down(v, 1);
        if ((tid & 63) == 0) red[tid >> 6][k] = v;
    }
    __syncthreads();
    if (tid == 0) {
        float t0[7];
        #pragma unroll
        for (int k = 0; k < 7; ++k)
            t0[k] = red[0][k] + red[1][k] + red[2][k] + red[3][k];
        float sum_sp = t0[0], sum_spt = t0[1], sum_st = t0[2], sum_stp = t0[3];
        float inter  = t0[4], sum_p   = t0[5], sum_t  = t0[6];
        float tprec = (sum_spt + 1.0f) / (sum_sp + 1.0f);
        float tsens = (sum_stp + 1.0f) / (sum_st + 1.0f);
        float cl    = 2.0f * tprec * tsens / (tprec + tsens + 1e-7f);
        float dice  = (2.0f * inter + 1.0f) / (sum_p + sum_t + 1.0f);
        out[0] = 1.0f - 0.5f * (dice + cl);
    }
}

extern "C" void kernel_launch(void* const* d_in, const int* in_sizes, int n_in,
                              void* d_out, int out_size, void* d_ws, size_t ws_size,
                              hipStream_t stream) {
    const float* pred = (const float*)d_in[0];
    const int*   targ = (const int*)d_in[1];
    float* ws  = (float*)d_ws;
    float* out = (float*)d_out;

    const int B = in_sizes[0] / (IMG * IMG);     // 8
    dim3 grid(IMG / TILE, IMG / TILE, B);        // 16 x 16 x 8 = 2048 blocks
    cl_dice_main<<<grid, 256, 0, stream>>>(pred, targ, ws);

    const int nblk = (IMG / TILE) * (IMG / TILE) * B;
    cl_dice_finalize<<<1, 256, 0, stream>>>(ws, out, nblk);
}

// Round 5
// 294.331 us; speedup vs baseline: 2.6845x; 2.6845x over previous
//
#include <hip/hip_runtime.h>
#include <math.h>

#define IMG   1024
#define TILE  64
#define HALO  12
#define BW    88            // TILE + 2*HALO
#define SP    48            // row stride in half2 pairs (44 real pairs padded to 48)
#define ROWS  90            // 1 guard row + 88 tile rows + 1 guard row
#define LDSN  (ROWS*SP)     // 4320 uint pairs = 17280 B per buffer
#define SEN2  0x40004000u   // half2(2.0, 2.0) : +inf sentinel (all real values <= 1)

typedef _Float16 h2 __attribute__((ext_vector_type(2)));

union UH { unsigned u; h2 h; };
__device__ __forceinline__ h2 u2h(unsigned u){ UH x; x.u = u; return x.h; }
__device__ __forceinline__ unsigned h2u(h2 h){ UH x; x.h = h; return x.u; }
__device__ __forceinline__ h2 pmin(h2 a, h2 b){ return __builtin_elementwise_min(a, b); }
__device__ __forceinline__ h2 pmax(h2 a, h2 b){ return __builtin_elementwise_max(a, b); }
// returns (lo_src.hi, hi_src.lo) — one v_alignbit_b32
__device__ __forceinline__ h2 funnel(h2 hi_src, h2 lo_src){
  return u2h((h2u(lo_src) >> 16) | (h2u(hi_src) << 16));
}
__device__ __forceinline__ float sigmoidf(float x){ return 1.0f / (1.0f + __expf(-x)); }

// 5-point-cross erode of 4 pixels (2 half2 pairs) at pair offset `off`.
// 5 LDS reads + 1 write + 3 alignbit + 8 pk_min for 4 pixels.
__device__ __forceinline__ void erode_dual(const unsigned* A, unsigned* B, int off){
  uint2 cu = *(const uint2*)&A[off];
  uint2 up = *(const uint2*)&A[off - SP];
  uint2 dn = *(const uint2*)&A[off + SP];
  unsigned pv = A[off - 1], nx = A[off + 2];
  h2 x  = u2h(cu.x), y = u2h(cu.y);
  h2 vx = pmin(u2h(up.x), u2h(dn.x));
  h2 vy = pmin(u2h(up.y), u2h(dn.y));
  h2 Lx = funnel(x, u2h(pv));            // (c-1, c0)
  h2 md = funnel(y, x);                  // (c1, c2)  = Rx = Ly
  h2 Ry = funnel(u2h(nx), y);            // (c3, c4)
  h2 hx = pmin(Lx, md);
  h2 hy = pmin(md, Ry);
  uint2 e;
  e.x = h2u(pmin(pmin(hx, vx), x));
  e.y = h2u(pmin(pmin(hy, vy), y));
  *(uint2*)&B[off] = e;
}

// soft_skeleton of one 64x64 tile (+12 halo) in packed fp16 LDS.
// MODE 0: sigmoid(pred); MODE 1: (float)target.  BND: tile touches image edge.
// Erode computes the full buffer with no region checks: garbage propagates
// inward one ring per step, and e_j is only consumed at rings >= j.
template<int MODE, bool BND>
__device__ void run_skel(const float* __restrict__ pred, const int* __restrict__ targ,
                         long base, int gr0, int gc0, int tid,
                         unsigned* A, unsigned* B,
                         h2 val[8], h2 skel[8]) {
  const int q  = tid & 31;
  const int rr = tid >> 5;

  // ---- global -> LDS (rows offset by 1 guard row) ----
  if (!BND) {
    #pragma unroll
    for (int k = 0; k < 11; ++k) {
      int r = rr + (k << 3);                       // 0..87
      if (q < 22) {                                // 22 x 4 px = 88 cols
        long gbase = base + (long)(gr0 + r) * IMG + gc0;
        unsigned lo, hi;
        if (MODE == 0) {
          float4 v = ((const float4*)(pred + gbase))[q];
          h2 a = {(_Float16)sigmoidf(v.x), (_Float16)sigmoidf(v.y)};
          h2 b = {(_Float16)sigmoidf(v.z), (_Float16)sigmoidf(v.w)};
          lo = h2u(a); hi = h2u(b);
        } else {
          int4 v = ((const int4*)(targ + gbase))[q];
          h2 a = {(_Float16)(float)v.x, (_Float16)(float)v.y};
          h2 b = {(_Float16)(float)v.z, (_Float16)(float)v.w};
          lo = h2u(a); hi = h2u(b);
        }
        uint2 w; w.x = lo; w.y = hi;
        *(uint2*)&A[(1 + r) * SP + (q << 1)] = w;
      }
    }
  } else {
    _Float16* Ah = (_Float16*)A;
    #pragma unroll
    for (int k = 0; k < 11; ++k) {
      int r = rr + (k << 3);
      int gr = gr0 + r;
      bool rok = (unsigned)gr < (unsigned)IMG;
      #pragma unroll
      for (int m = 0; m < 3; ++m) {
        int c = q + (m << 5);
        if (c < BW) {
          int gc = gc0 + c;
          _Float16 hv = (_Float16)2.0f;            // +inf sentinel
          if (rok && (unsigned)gc < (unsigned)IMG) {
            float f = (MODE == 0) ? sigmoidf(pred[base + (long)gr * IMG + gc])
                                  : (float)targ[base + (long)gr * IMG + gc];
            hv = (_Float16)f;
          }
          Ah[(1 + r) * (SP * 2) + c] = hv;
        }
      }
    }
  }
  __syncthreads();

  // interior pixel ownership: pair-col pc in [6,37], 8-row strip per thread
  const int pc = 6 + (tid & 31);
  const int rg = tid >> 5;
  #pragma unroll
  for (int k = 0; k < 8; ++k) val[k] = u2h(A[(13 + (rg << 3) + k) * SP + pc]);

  const h2 onev  = {(_Float16)1.0f, (_Float16)1.0f};
  const h2 zerov = {(_Float16)0.0f, (_Float16)0.0f};

  for (int j = 1; j <= 11; ++j) {
    // ---- erode A -> B over all 88 tile rows (2112 dual-pairs) ----
    #pragma unroll
    for (int k = 0; k < 8; ++k) erode_dual(A, B, SP + ((tid + (k << 8)) << 1));
    if (tid < 64) erode_dual(A, B, SP + ((tid + 2048) << 1));
    __syncthreads();

    if (BND) {
      // re-stamp out-of-image rows/cols to +inf sentinel (boundaries are pair-aligned)
      if (gr0 < 0)        for (int i = tid; i < 12 * SP; i += 256) B[SP + i] = SEN2;
      if (gr0 + BW > IMG) for (int i = tid; i < 12 * SP; i += 256) B[77 * SP + i] = SEN2;
      if (gc0 < 0)        for (int i = tid; i < BW * 6; i += 256) { int r5 = i / 6; B[(1 + r5) * SP + (i - r5 * 6)] = SEN2; }
      if (gc0 + BW > IMG) for (int i = tid; i < BW * 6; i += 256) { int r5 = i / 6; B[(1 + r5) * SP + 38 + (i - r5 * 6)] = SEN2; }
      __syncthreads();
    }

    // ---- separable 3x3 dilate of B at interior + skel update ----
    h2 h[10];
    #pragma unroll
    for (int k = 0; k < 10; ++k) {
      int off = (12 + (rg << 3) + k) * SP + pc;
      h2 c = u2h(B[off]), p = u2h(B[off - 1]), n = u2h(B[off + 1]);
      if (BND) {
        // sentinel(2.0) -> 0, identity on [0,1]: t=max(c-1,0); c -= 2t  (exact in fp16)
        h2 tc = pmax(c - onev, zerov); c = c - tc - tc;
        h2 tp = pmax(p - onev, zerov); p = p - tp - tp;
        h2 tn = pmax(n - onev, zerov); n = n - tn - tn;
      }
      h[k] = pmax(pmax(funnel(c, p), funnel(n, c)), c);
    }
    #pragma unroll
    for (int k = 0; k < 8; ++k) {
      h2 m  = pmax(pmax(h[k], h[k + 1]), h[k + 2]);
      h2 ep = u2h(A[(13 + (rg << 3) + k) * SP + pc]);   // e_{j-1}
      h2 d  = pmax(ep - m, zerov);                      // relu(e_prev - open)
      if (j == 1) skel[k] = d;
      else {
        h2 t1 = d - skel[k] * d;
        skel[k] = skel[k] + pmax(t1, zerov);
      }
    }
    __syncthreads();
    unsigned* t = A; A = B; B = t;
  }
}

__global__ __launch_bounds__(256)
void cl_dice_main(const float* __restrict__ pred, const int* __restrict__ targ,
                  float* __restrict__ ws) {
  __shared__ unsigned sA[LDSN];
  __shared__ unsigned sB[LDSN];
  const int tid = threadIdx.x;
  const int gr0 = blockIdx.y * TILE - HALO;
  const int gc0 = blockIdx.x * TILE - HALO;
  const long base = (long)blockIdx.z * (long)(IMG * IMG);

  h2 vp[8], kp[8], vt[8], kt[8];
  const bool bnd = (blockIdx.x == 0) | (blockIdx.x == gridDim.x - 1) |
                   (blockIdx.y == 0) | (blockIdx.y == gridDim.y - 1);
  if (!bnd) {
    run_skel<0, false>(pred, targ, base, gr0, gc0, tid, sA, sB, vp, kp);
    run_skel<1, false>(pred, targ, base, gr0, gc0, tid, sA, sB, vt, kt);
  } else {
    run_skel<0, true >(pred, targ, base, gr0, gc0, tid, sA, sB, vp, kp);
    run_skel<1, true >(pred, targ, base, gr0, gc0, tid, sA, sB, vt, kt);
  }

  float s[7] = {0, 0, 0, 0, 0, 0, 0};
  #pragma unroll
  for (int k = 0; k < 8; ++k) {
    float px = (float)vp[k].x, py = (float)vp[k].y;
    float tx = (float)vt[k].x, ty = (float)vt[k].y;
    float ax = (float)kp[k].x, ay = (float)kp[k].y;
    float bx = (float)kt[k].x, by = (float)kt[k].y;
    s[0] += ax + ay;
    s[1] += ax * tx + ay * ty;
    s[2] += bx + by;
    s[3] += bx * px + by * py;
    s[4] += px * tx + py * ty;
    s[5] += px + py;
    s[6] += tx + ty;
  }

  float* red = (float*)sA;
  #pragma unroll
  for (int k = 0; k < 7; ++k) {
    float v = s[k];
    v += __shfl_down(v, 32); v += __shfl_down(v, 16); v += __shfl_down(v, 8);
    v += __shfl_down(v, 4);  v += __shfl_down(v, 2);  v += __shfl_down(v, 1);
    if ((tid & 63) == 0) red[(tid >> 6) * 8 + k] = v;
  }
  __syncthreads();
  if (tid < 7) {
    float v = red[tid] + red[8 + tid] + red[16 + tid] + red[24 + tid];
    int blk = (blockIdx.z * gridDim.y + blockIdx.y) * gridDim.x + blockIdx.x;
    ws[blk * 8 + tid] = v;
  }
}

__global__ __launch_bounds__(256)
void cl_dice_finalize(const float* __restrict__ ws, float* __restrict__ out, int nblk) {
  __shared__ float red[4][8];
  int tid = threadIdx.x;
  float acc[7] = {0, 0, 0, 0, 0, 0, 0};
  for (int i = tid; i < nblk; i += 256) {
    #pragma unroll
    for (int k = 0; k < 7; ++k) acc[k] += ws[i * 8 + k];
  }
  #pragma unroll
  for (int k = 0; k < 7; ++k) {
    float v = acc[k];
    v += __shfl_down(v, 32); v += __shfl_down(v, 16); v += __shfl_down(v, 8);
    v += __shfl_down(v, 4);  v += __shfl_down(v, 2);  v += __shfl_down(v, 1);
    if ((tid & 63) == 0) red[tid >> 6][k] = v;
  }
  __syncthreads();
  if (tid == 0) {
    float t0[7];
    #pragma unroll
    for (int k = 0; k < 7; ++k)
      t0[k] = red[0][k] + red[1][k] + red[2][k] + red[3][k];
    float sum_sp = t0[0], sum_spt = t0[1], sum_st = t0[2], sum_stp = t0[3];
    float inter  = t0[4], sum_p   = t0[5], sum_t  = t0[6];
    float tprec = (sum_spt + 1.0f) / (sum_sp + 1.0f);
    float tsens = (sum_stp + 1.0f) / (sum_st + 1.0f);
    float cl    = 2.0f * tprec * tsens / (tprec + tsens + 1e-7f);
    float dice  = (2.0f * inter + 1.0f) / (sum_p + sum_t + 1.0f);
    out[0] = 1.0f - 0.5f * (dice + cl);
  }
}

extern "C" void kernel_launch(void* const* d_in, const int* in_sizes, int n_in,
                              void* d_out, int out_size, void* d_ws, size_t ws_size,
                              hipStream_t stream) {
  const float* pred = (const float*)d_in[0];
  const int*   targ = (const int*)d_in[1];
  float* ws  = (float*)d_ws;
  float* out = (float*)d_out;

  const int B = in_sizes[0] / (IMG * IMG);       // 8
  dim3 grid(IMG / TILE, IMG / TILE, B);          // 16 x 16 x 8 = 2048 blocks
  cl_dice_main<<<grid, 256, 0, stream>>>(pred, targ, ws);

  const int nblk = (IMG / TILE) * (IMG / TILE) * B;
  cl_dice_finalize<<<1, 256, 0, stream>>>(ws, out, nblk);
}